// Round 11
// baseline (5205.222 us; speedup 1.0000x reference)
//
#include <hip/hip_runtime.h>
#include <cstdint>

#define DEVFN static __device__ __forceinline__
typedef unsigned short ushort_t;
typedef unsigned int uint_t;
typedef short short8 __attribute__((ext_vector_type(8)));
typedef float f32x4 __attribute__((ext_vector_type(4)));

DEVFN float bf2f(ushort_t h) { return __uint_as_float(((uint_t)h) << 16); }
DEVFN ushort_t bfhi(float f) {
    uint_t u = __float_as_uint(f);
    u += 0x7fffu + ((u >> 16) & 1u);
    return (ushort_t)(u >> 16);
}
DEVFN void fsplit(float f, ushort_t& h, ushort_t& l) {
    h = bfhi(f);
    l = bfhi(f - bf2f(h));
}
// relu on a packed pair of bf16 hi/lo dwords (2 elements each)
DEVFN void relu_pair(uint_t& h, uint_t& l) {
    float f0 = bf2f((ushort_t)(h & 0xffffu)) + bf2f((ushort_t)(l & 0xffffu));
    float f1 = bf2f((ushort_t)(h >> 16)) + bf2f((ushort_t)(l >> 16));
    if (f0 <= 0.f) { h &= 0xffff0000u; l &= 0xffff0000u; }
    if (f1 <= 0.f) { h &= 0x0000ffffu; l &= 0x0000ffffu; }
}
// XCD chunked swizzle (T1) — adjacent t-tiles to the same XCD L2.
// VERIFIED R5: FETCH 145->37 MB on L=32768 convs. Bijective iff gx%8==0.
DEVFN int xcd_swz(int bx, int gx) {
    return ((gx & 7) == 0) ? ((bx & 7) * (gx >> 3) + (bx >> 3)) : bx;
}

// ============================================================================
// weight prep: fp32 [co][ci][k] -> bf16 hi/lo [tap][co][ci]
// ============================================================================
__global__ __launch_bounds__(256)
void wprep3_k(const float* __restrict__ erw, const float* __restrict__ drw,
              ushort_t* __restrict__ wH, ushort_t* __restrict__ wL)
{
    const int gid = blockIdx.x * 256 + threadIdx.x;   // 80*65536 threads
    const int conv = gid >> 16;
    const int rem  = gid & 65535;                      // co*256+ci
    const int co = rem >> 8, ci = rem & 255;
    const float* src = (conv < 40) ? (erw + (size_t)conv * 196608)
                                   : (drw + (size_t)(conv - 40) * 196608);
    const float* p = src + ((size_t)co * 256 + ci) * 3;
    ushort_t* oh = wH + (size_t)conv * 196608 + rem;
    ushort_t* ol = wL + (size_t)conv * 196608 + rem;
#pragma unroll
    for (int k = 0; k < 3; ++k) {
        ushort_t h, l; fsplit(p[k], h, l);
        oh[k * 65536] = h; ol[k * 65536] = l;
    }
}

__global__ __launch_bounds__(256)
void wprep4_k(const float* __restrict__ edw, const float* __restrict__ duw,
              ushort_t* __restrict__ wH, ushort_t* __restrict__ wL)
{
    const int gid = blockIdx.x * 256 + threadIdx.x;   // 8*65536 threads
    const int conv = gid >> 16;
    const int rem  = gid & 65535;
    const int co = rem >> 8, ci = rem & 255;
    ushort_t* oh = wH + (size_t)conv * 262144 + rem;
    ushort_t* ol = wL + (size_t)conv * 262144 + rem;
#pragma unroll
    for (int k = 0; k < 4; ++k) {
        float f;
        if (conv < 4)  f = edw[(size_t)conv * 262144 + ((size_t)co * 256 + ci) * 4 + k];
        else           f = duw[(size_t)(conv - 4) * 262144 + ((size_t)ci * 256 + co) * 4 + k];
        ushort_t h, l; fsplit(f, h, l);
        oh[k * 65536] = h; ol[k * 65536] = l;
    }
}

// ============================================================================
// split-precision MFMA conv.
// act layout [b][t][256c] bf16 hi/lo. Block: NT*16 t x 256 co, 4 waves x 64co.
// (R8/R9/R10-verified: T1 XCD swizzle, DBUF prefetch d<=27, T5 setprio,
// paired epilogue. R11: unchanged.)
// ============================================================================
template<int TAPS, int STRIDE, bool RELU, int NT, int DMAX, bool DBUF>
__global__ __launch_bounds__(256, (NT >= 8) ? 2 : 3)
void convs_k(const ushort_t* __restrict__ inH, const ushort_t* __restrict__ inL,
             const ushort_t* __restrict__ wH, const ushort_t* __restrict__ wL,
             const float* __restrict__ bias,
             const ushort_t* __restrict__ srcH, const ushort_t* __restrict__ srcL,
             float alpha,
             ushort_t* __restrict__ outH, ushort_t* __restrict__ outL,
             int Lin, int Lout, int dil, int pad)
{
    constexpr int ROWS = NT * 16;
    constexpr int SMAX = STRIDE * (ROWS - 1) + (TAPS - 1) * DMAX + 1;
    constexpr int XSB  = SMAX * 80;          // bytes per plane per buffer
    constexpr int NEED = DBUF ? 4 * XSB : 2 * XSB;
    constexpr int EMIN = (NT >= 2) ? 33280 : 16640;   // epilogue rows x 260 x 4B
    constexpr int ARENA = (NEED > EMIN) ? NEED : EMIN;
    static_assert(!DBUF || (4 * SMAX <= TAPS * 256), "prefetch item budget");
    __shared__ __align__(16) char sarena[ARENA];

    const int tid = threadIdx.x;
    const int b = blockIdx.z;
    const int t0 = xcd_swz(blockIdx.x, gridDim.x) * ROWS;
    const int wave = tid >> 6, lane = tid & 63;
    const int quad = lane >> 4, lr = lane & 15;
    const int cow = wave * 64;
    const size_t inbase = (size_t)b * Lin * 256;
    const int S = STRIDE * (ROWS - 1) + (TAPS - 1) * dil + 1;
    const int g0 = STRIDE * t0 - pad;

    f32x4 acc[4][NT];
#pragma unroll
    for (int m = 0; m < 4; ++m)
#pragma unroll
        for (int n = 0; n < NT; ++n) acc[m][n] = (f32x4)0.f;

    if constexpr (DBUF) {
        ushort_t (*xsH0)[40] = (ushort_t(*)[40])(sarena);
        ushort_t (*xsL0)[40] = (ushort_t(*)[40])(sarena + XSB);
        ushort_t (*xsH1)[40] = (ushort_t(*)[40])(sarena + 2 * XSB);
        ushort_t (*xsL1)[40] = (ushort_t(*)[40])(sarena + 3 * XSB);
        // ---- prologue: stage chunk 0 into buffer 0 ----
        for (int idx = tid; idx < S * 4; idx += 256) {
            const int s = idx >> 2, p = idx & 3;
            const int t = g0 + s;
            uint4 hv = make_uint4(0, 0, 0, 0), lv = hv;
            if (t >= 0 && t < Lin) {
                const size_t g = inbase + (size_t)t * 256 + p * 8;
                hv = *(const uint4*)(inH + g);
                lv = *(const uint4*)(inL + g);
                if (RELU) {
                    relu_pair(hv.x, lv.x); relu_pair(hv.y, lv.y);
                    relu_pair(hv.z, lv.z); relu_pair(hv.w, lv.w);
                }
            }
            *(uint4*)&xsH0[s][p * 8] = hv;
            *(uint4*)&xsL0[s][p * 8] = lv;
        }
        __syncthreads();
        for (int chunk = 0; chunk < 8; ++chunk) {
            const int ci0 = chunk * 32;
            ushort_t (*xsH)[40] = (chunk & 1) ? xsH1 : xsH0;
            ushort_t (*xsL)[40] = (chunk & 1) ? xsL1 : xsL0;
            ushort_t (*xnH)[40] = (chunk & 1) ? xsH0 : xsH1;
            ushort_t (*xnL)[40] = (chunk & 1) ? xsL0 : xsL1;
            const bool pf = (chunk < 7);
#pragma unroll
            for (int tap = 0; tap < TAPS; ++tap) {
                // A fragments FIRST (their waitcnt shouldn't drain prefetch)
                const ushort_t* wHt = wH + (size_t)tap * 65536 + ci0 + quad * 8;
                const ushort_t* wLt = wL + (size_t)tap * 65536 + ci0 + quad * 8;
                short8 aH[4], aL[4];
#pragma unroll
                for (int m = 0; m < 4; ++m) {
                    const int co = cow + m * 16 + lr;
                    aH[m] = *(const short8*)(wHt + co * 256);
                    aL[m] = *(const short8*)(wLt + co * 256);
                }
                // issue next-chunk prefetch (this tap's item slice)
                const int idx = tap * 256 + tid;
                const int s = idx >> 2, p = idx & 3;
                const int tr = g0 + s;
                const bool inr = (idx < S * 4);
                uint4 hv = make_uint4(0, 0, 0, 0), lv = hv;
                if (pf && inr && tr >= 0 && tr < Lin) {
                    const size_t g = inbase + (size_t)tr * 256 + (ci0 + 32) + p * 8;
                    hv = *(const uint4*)(inH + g);
                    lv = *(const uint4*)(inL + g);
                }
                // compute this tap (hides prefetch latency)
                const int rb = tap * dil;
                __builtin_amdgcn_s_setprio(1);
#pragma unroll
                for (int n = 0; n < NT; ++n) {
                    const int srow = STRIDE * (n * 16 + lr) + rb;
                    const short8 bH = *(const short8*)&xsH[srow][quad * 8];
                    const short8 bL = *(const short8*)&xsL[srow][quad * 8];
#pragma unroll
                    for (int m = 0; m < 4; ++m)
                        acc[m][n] = __builtin_amdgcn_mfma_f32_16x16x32_bf16(aH[m], bH, acc[m][n], 0, 0, 0);
#pragma unroll
                    for (int m = 0; m < 4; ++m)
                        acc[m][n] = __builtin_amdgcn_mfma_f32_16x16x32_bf16(aH[m], bL, acc[m][n], 0, 0, 0);
#pragma unroll
                    for (int m = 0; m < 4; ++m)
                        acc[m][n] = __builtin_amdgcn_mfma_f32_16x16x32_bf16(aL[m], bH, acc[m][n], 0, 0, 0);
                }
                __builtin_amdgcn_s_setprio(0);
                // land prefetched data in the other buffer
                if (pf && inr) {
                    if (RELU) {
                        relu_pair(hv.x, lv.x); relu_pair(hv.y, lv.y);
                        relu_pair(hv.z, lv.z); relu_pair(hv.w, lv.w);
                    }
                    *(uint4*)&xnH[s][p * 8] = hv;
                    *(uint4*)&xnL[s][p * 8] = lv;
                }
            }
            __syncthreads();   // one barrier per chunk
        }
    } else {
        // ---- single-buffer path (d=81, conv4) ----
        ushort_t (*xsH)[40] = (ushort_t(*)[40])(sarena);
        ushort_t (*xsL)[40] = (ushort_t(*)[40])(sarena + XSB);
        for (int chunk = 0; chunk < 8; ++chunk) {
            const int ci0 = chunk * 32;
            __syncthreads();
            for (int idx = tid; idx < S * 4; idx += 256) {
                const int s = idx >> 2, p = idx & 3;
                const int t = g0 + s;
                uint4 hv = make_uint4(0, 0, 0, 0), lv = hv;
                if (t >= 0 && t < Lin) {
                    const size_t g = inbase + (size_t)t * 256 + ci0 + p * 8;
                    hv = *(const uint4*)(inH + g);
                    lv = *(const uint4*)(inL + g);
                    if (RELU) {
                        relu_pair(hv.x, lv.x); relu_pair(hv.y, lv.y);
                        relu_pair(hv.z, lv.z); relu_pair(hv.w, lv.w);
                    }
                }
                *(uint4*)&xsH[s][p * 8] = hv;
                *(uint4*)&xsL[s][p * 8] = lv;
            }
            __syncthreads();
#pragma unroll
            for (int tap = 0; tap < TAPS; ++tap) {
                const ushort_t* wHt = wH + (size_t)tap * 65536 + ci0 + quad * 8;
                const ushort_t* wLt = wL + (size_t)tap * 65536 + ci0 + quad * 8;
                short8 aH[4], aL[4];
#pragma unroll
                for (int m = 0; m < 4; ++m) {
                    const int co = cow + m * 16 + lr;
                    aH[m] = *(const short8*)(wHt + co * 256);
                    aL[m] = *(const short8*)(wLt + co * 256);
                }
                const int rb = tap * dil;
                __builtin_amdgcn_s_setprio(1);
#pragma unroll
                for (int n = 0; n < NT; ++n) {
                    const int srow = STRIDE * (n * 16 + lr) + rb;
                    const short8 bH = *(const short8*)&xsH[srow][quad * 8];
                    const short8 bL = *(const short8*)&xsL[srow][quad * 8];
#pragma unroll
                    for (int m = 0; m < 4; ++m)
                        acc[m][n] = __builtin_amdgcn_mfma_f32_16x16x32_bf16(aH[m], bH, acc[m][n], 0, 0, 0);
#pragma unroll
                    for (int m = 0; m < 4; ++m)
                        acc[m][n] = __builtin_amdgcn_mfma_f32_16x16x32_bf16(aH[m], bL, acc[m][n], 0, 0, 0);
#pragma unroll
                    for (int m = 0; m < 4; ++m)
                        acc[m][n] = __builtin_amdgcn_mfma_f32_16x16x32_bf16(aL[m], bH, acc[m][n], 0, 0, 0);
                }
                __builtin_amdgcn_s_setprio(0);
            }
        }
    }
    // ---- coalesced epilogue ----
    float4 bvv[4];
#pragma unroll
    for (int m = 0; m < 4; ++m)
        bvv[m] = *(const float4*)&bias[cow + m * 16 + quad * 4];
    __syncthreads();
    if constexpr (NT >= 2) {
        // paired n-groups -> 32-row ebuf, half the barriers (unrolled: rule #20)
        float (*ebuf)[260] = (float(*)[260])sarena;   // 32 rows x 260 cols
#pragma unroll
        for (int n2 = 0; n2 < NT; n2 += 2) {
#pragma unroll
            for (int half = 0; half < 2; ++half) {
                const int n = n2 + half;
#pragma unroll
                for (int m = 0; m < 4; ++m) {
                    float4 v;
                    v.x = acc[m][n][0] + bvv[m].x;
                    v.y = acc[m][n][1] + bvv[m].y;
                    v.z = acc[m][n][2] + bvv[m].z;
                    v.w = acc[m][n][3] + bvv[m].w;
                    *(float4*)&ebuf[16 * half + lr][cow + m * 16 + quad * 4] = v;
                }
            }
            __syncthreads();
#pragma unroll
            for (int h = 0; h < 8; ++h) {
                const int row = (tid >> 4) + 16 * (h >> 2);
                const int col = (tid & 15) * 4 + (h & 3) * 64;
                const int t = t0 + n2 * 16 + row;
                const size_t gr = ((size_t)b * Lout + t) * 256;
                float4 v = *(const float4*)&ebuf[row][col];
                if (alpha != 0.f) {
                    const ushort4 sh = *(const ushort4*)(srcH + gr + col);
                    const ushort4 sl = *(const ushort4*)(srcL + gr + col);
                    v.x += alpha * (bf2f(sh.x) + bf2f(sl.x));
                    v.y += alpha * (bf2f(sh.y) + bf2f(sl.y));
                    v.z += alpha * (bf2f(sh.z) + bf2f(sl.z));
                    v.w += alpha * (bf2f(sh.w) + bf2f(sl.w));
                }
                ushort4 oh, ol;
                fsplit(v.x, oh.x, ol.x); fsplit(v.y, oh.y, ol.y);
                fsplit(v.z, oh.z, ol.z); fsplit(v.w, oh.w, ol.w);
                *(ushort4*)(outH + gr + col) = oh;
                *(ushort4*)(outL + gr + col) = ol;
            }
            __syncthreads();
        }
    } else {
        float (*ebuf)[260] = (float(*)[260])sarena;   // 16 rows x 260 cols
#pragma unroll
        for (int n = 0; n < NT; ++n) {
#pragma unroll
            for (int m = 0; m < 4; ++m) {
                float4 v;
                v.x = acc[m][n][0] + bvv[m].x;
                v.y = acc[m][n][1] + bvv[m].y;
                v.z = acc[m][n][2] + bvv[m].z;
                v.w = acc[m][n][3] + bvv[m].w;
                *(float4*)&ebuf[lr][cow + m * 16 + quad * 4] = v;
            }
            __syncthreads();
            {
                const int row = tid >> 4;
                const int c00 = (tid & 15) * 4;
                const int t = t0 + n * 16 + row;
                const size_t gr = ((size_t)b * Lout + t) * 256;
#pragma unroll
                for (int rep = 0; rep < 4; ++rep) {
                    const int col = c00 + rep * 64;
                    float4 v = *(const float4*)&ebuf[row][col];
                    if (alpha != 0.f) {
                        const ushort4 sh = *(const ushort4*)(srcH + gr + col);
                        const ushort4 sl = *(const ushort4*)(srcL + gr + col);
                        v.x += alpha * (bf2f(sh.x) + bf2f(sl.x));
                        v.y += alpha * (bf2f(sh.y) + bf2f(sl.y));
                        v.z += alpha * (bf2f(sh.z) + bf2f(sl.z));
                        v.w += alpha * (bf2f(sh.w) + bf2f(sl.w));
                    }
                    ushort4 oh, ol;
                    fsplit(v.x, oh.x, ol.x); fsplit(v.y, oh.y, ol.y);
                    fsplit(v.z, oh.z, ol.z); fsplit(v.w, oh.w, ol.w);
                    *(ushort4*)(outH + gr + col) = oh;
                    *(ushort4*)(outL + gr + col) = ol;
                }
            }
            __syncthreads();
        }
    }
}

// ============================================================================
// conv transpose k=4 s=2 p=1 (split MFMA). Block: NTc*16 input m x 256 co.
// out[2m]   = x[m]w1 + x[m-1]w3 ; out[2m+1] = x[m+1]w0 + x[m]w2
// (R10 verbatim)
// ============================================================================
template<int NTc>
__global__ __launch_bounds__(256, 2)
void convt_k(const ushort_t* __restrict__ inH, const ushort_t* __restrict__ inL,
             const ushort_t* __restrict__ wH, const ushort_t* __restrict__ wL,
             const float* __restrict__ bias,
             ushort_t* __restrict__ outH, ushort_t* __restrict__ outL, int Lin)
{
    constexpr int ROWS = NTc * 16;
    constexpr int S = ROWS + 2;
    constexpr int XSB = S * 40 * 2;
    constexpr int ARENA = (2 * XSB > 33280) ? 2 * XSB : 33280;
    __shared__ __align__(16) char sarena[ARENA];
    ushort_t (*xsH)[40] = (ushort_t(*)[40])(sarena);
    ushort_t (*xsL)[40] = (ushort_t(*)[40])(sarena + XSB);

    const int tid = threadIdx.x;
    const int b = blockIdx.z;
    const int m0 = xcd_swz(blockIdx.x, gridDim.x) * ROWS;
    const int Lout = Lin * 2;
    const int wave = tid >> 6, lane = tid & 63;
    const int quad = lane >> 4, lr = lane & 15;
    const int cow = wave * 64;
    const size_t inbase = (size_t)b * Lin * 256;

    f32x4 acc[4][NTc][2];
#pragma unroll
    for (int m = 0; m < 4; ++m)
#pragma unroll
        for (int n = 0; n < NTc; ++n) { acc[m][n][0] = (f32x4)0.f; acc[m][n][1] = (f32x4)0.f; }

    for (int chunk = 0; chunk < 8; ++chunk) {
        const int ci0 = chunk * 32;
        __syncthreads();
        for (int idx = tid; idx < S * 4; idx += 256) {
            const int s = idx >> 2, p = idx & 3;
            const int t = m0 - 1 + s;
            uint4 hv = make_uint4(0, 0, 0, 0), lv = hv;
            if (t >= 0 && t < Lin) {
                const size_t g = inbase + (size_t)t * 256 + ci0 + p * 8;
                hv = *(const uint4*)(inH + g);
                lv = *(const uint4*)(inL + g);
            }
            *(uint4*)&xsH[s][p * 8] = hv;
            *(uint4*)&xsL[s][p * 8] = lv;
        }
        __syncthreads();
#pragma unroll
        for (int tap = 0; tap < 4; ++tap) {
            const int ph = (tap == 0 || tap == 2) ? 1 : 0;   // PHASE = {1,0,1,0}
            const int sh = (tap == 0) ? 1 : ((tap == 3) ? -1 : 0);  // SHIFT
            const ushort_t* wHt = wH + (size_t)tap * 65536 + ci0 + quad * 8;
            const ushort_t* wLt = wL + (size_t)tap * 65536 + ci0 + quad * 8;
            short8 aH[4], aL[4];
#pragma unroll
            for (int m = 0; m < 4; ++m) {
                const int co = cow + m * 16 + lr;
                aH[m] = *(const short8*)(wHt + co * 256);
                aL[m] = *(const short8*)(wLt + co * 256);
            }
            __builtin_amdgcn_s_setprio(1);
#pragma unroll
            for (int n = 0; n < NTc; ++n) {
                const int srow = n * 16 + lr + sh + 1;
                const short8 bH = *(const short8*)&xsH[srow][quad * 8];
                const short8 bL = *(const short8*)&xsL[srow][quad * 8];
#pragma unroll
                for (int m = 0; m < 4; ++m)
                    acc[m][n][ph] = __builtin_amdgcn_mfma_f32_16x16x32_bf16(aH[m], bH, acc[m][n][ph], 0, 0, 0);
#pragma unroll
                for (int m = 0; m < 4; ++m)
                    acc[m][n][ph] = __builtin_amdgcn_mfma_f32_16x16x32_bf16(aH[m], bL, acc[m][n][ph], 0, 0, 0);
#pragma unroll
                for (int m = 0; m < 4; ++m)
                    acc[m][n][ph] = __builtin_amdgcn_mfma_f32_16x16x32_bf16(aL[m], bH, acc[m][n][ph], 0, 0, 0);
            }
            __builtin_amdgcn_s_setprio(0);
        }
    }
    // ---- coalesced epilogue: 32 output rows per n-group ----
    float4 bvv[4];
#pragma unroll
    for (int m = 0; m < 4; ++m)
        bvv[m] = *(const float4*)&bias[cow + m * 16 + quad * 4];
    __syncthreads();
    float (*ebuf)[260] = (float(*)[260])sarena;   // 32 rows x 260 cols
#pragma unroll
    for (int n = 0; n < NTc; ++n) {
#pragma unroll
        for (int m = 0; m < 4; ++m) {
#pragma unroll
            for (int ph = 0; ph < 2; ++ph) {
                float4 v;
                v.x = acc[m][n][ph][0] + bvv[m].x;
                v.y = acc[m][n][ph][1] + bvv[m].y;
                v.z = acc[m][n][ph][2] + bvv[m].z;
                v.w = acc[m][n][ph][3] + bvv[m].w;
                *(float4*)&ebuf[2 * lr + ph][cow + m * 16 + quad * 4] = v;
            }
        }
        __syncthreads();
        {
            const int baset = 2 * (m0 + n * 16);
#pragma unroll
            for (int h = 0; h < 8; ++h) {
                const int row = (tid >> 4) + 16 * (h >> 2);
                const int col = (tid & 15) * 4 + (h & 3) * 64;
                const int t = baset + row;
                const size_t gr = ((size_t)b * Lout + t) * 256 + col;
                float4 v = *(const float4*)&ebuf[row][col];
                ushort4 oh, ol;
                fsplit(v.x, oh.x, ol.x); fsplit(v.y, oh.y, ol.y);
                fsplit(v.z, oh.z, ol.z); fsplit(v.w, oh.w, ol.w);
                *(ushort4*)(outH + gr) = oh;
                *(ushort4*)(outL + gr) = ol;
            }
        }
        __syncthreads();
    }
}

// ============================================================================
// first conv 1->256 k=4 s=2 p=1 ; writes [b][t][c] hi/lo
// ============================================================================
__global__ __launch_bounds__(256)
void down0_k2(const float* __restrict__ x, const float* __restrict__ w,
              const float* __restrict__ bias,
              ushort_t* __restrict__ outH, ushort_t* __restrict__ outL)
{
    const int t = blockIdx.x;               // 32768
    const int b = blockIdx.y;
    const int co = threadIdx.x;
    const float* xb = x + (size_t)b * 65536;
    const float4 wv = *(const float4*)(w + co * 4);
    float s = bias[co];
    const int ti0 = 2 * t - 1;
    if (ti0 >= 0)      s = fmaf(xb[ti0], wv.x, s);
    s = fmaf(xb[ti0 + 1], wv.y, s);
    s = fmaf(xb[ti0 + 2], wv.z, s);
    if (ti0 + 3 < 65536) s = fmaf(xb[ti0 + 3], wv.w, s);
    ushort_t h, l; fsplit(s, h, l);
    const size_t g = ((size_t)b * 32768 + t) * 256 + co;
    outH[g] = h; outL[g] = l;
}

// ============================================================================
// last conv transpose 256->1
// ============================================================================
__global__ __launch_bounds__(256)
void uplast_k2(const ushort_t* __restrict__ inH, const ushort_t* __restrict__ inL,
               const float* __restrict__ w, const float* __restrict__ bias,
               float* __restrict__ out, int Lin)
{
    const int m = blockIdx.x * 256 + threadIdx.x;
    const int b = blockIdx.y;
    const float bv = bias[0];
    float aE = bv, aO = bv;
    const size_t base = (size_t)b * Lin * 256;
    const ushort_t* r0H = inH + base + (size_t)m * 256;
    const ushort_t* r0L = inL + base + (size_t)m * 256;
    const bool hasM = (m > 0), hasP = (m + 1 < Lin);
    for (int c0 = 0; c0 < 256; c0 += 8) {
        uint4 h0 = *(const uint4*)(r0H + c0);
        uint4 l0 = *(const uint4*)(r0L + c0);
        uint4 hm = make_uint4(0,0,0,0), lm = hm, hp = hm, lp = hm;
        if (hasM) { hm = *(const uint4*)(r0H - 256 + c0); lm = *(const uint4*)(r0L - 256 + c0); }
        if (hasP) { hp = *(const uint4*)(r0H + 256 + c0); lp = *(const uint4*)(r0L + 256 + c0); }
        const uint_t* h0p = (const uint_t*)&h0; const uint_t* l0p = (const uint_t*)&l0;
        const uint_t* hmp = (const uint_t*)&hm; const uint_t* lmp = (const uint_t*)&lm;
        const uint_t* hpp = (const uint_t*)&hp; const uint_t* lpp = (const uint_t*)&lp;
#pragma unroll
        for (int e = 0; e < 4; ++e) {
#pragma unroll
            for (int half = 0; half < 2; ++half) {
                const int sh = half * 16;
                const int ci = c0 + e * 2 + half;
                const float x0  = bf2f((ushort_t)(h0p[e] >> sh)) + bf2f((ushort_t)(l0p[e] >> sh));
                const float xm1 = bf2f((ushort_t)(hmp[e] >> sh)) + bf2f((ushort_t)(lmp[e] >> sh));
                const float xp1 = bf2f((ushort_t)(hpp[e] >> sh)) + bf2f((ushort_t)(lpp[e] >> sh));
                const float4 wv = *(const float4*)(w + ci * 4);
                aE = fmaf(x0, wv.y, fmaf(xm1, wv.w, aE));
                aO = fmaf(xp1, wv.x, fmaf(x0, wv.z, aO));
            }
        }
    }
    *(float2*)(out + (size_t)b * 2 * Lin + 2 * m) = make_float2(aE, aO);
}

// ============================================================================
// RVQ (fp32)
// ============================================================================
// all 8 codebooks in ONE dispatch
__global__ __launch_bounds__(256)
void rvq_cb_all_k(const float* __restrict__ sum, const float* __restrict__ usage,
                  float* __restrict__ cb, float* __restrict__ cbT,
                  float* __restrict__ cbn)
{
    const int k = blockIdx.x, iq = blockIdx.y, c = threadIdx.x;
    const float den = fmaxf(usage[iq * 1024 + k], 1e-5f);
    const float v = sum[((size_t)iq * 1024 + k) * 256 + c] / den;
    cb[(size_t)iq * 262144 + (size_t)k * 256 + c] = v;
    cbT[(size_t)iq * 262144 + (size_t)c * 1024 + k] = v;
    float s = v * v;
    for (int off = 32; off; off >>= 1) s += __shfl_down(s, off, 64);
    __shared__ float ls[4];
    if ((c & 63) == 0) ls[c >> 6] = s;
    __syncthreads();
    if (c == 0) cbn[iq * 1024 + k] = ls[0] + ls[1] + ls[2] + ls[3];
}

DEVFN unsigned int ordbits(float f)
{
    unsigned u = __float_as_uint(f);
    return (u & 0x80000000u) ? ~u : (u | 0x80000000u);
}
DEVFN unsigned long long shfl_xor_u64(unsigned long long v, int mask)
{
    int lo = (int)(v & 0xffffffffull), hi = (int)(v >> 32);
    lo = __shfl_xor(lo, mask, 64);
    hi = __shfl_xor(hi, mask, 64);
    return ((unsigned long long)(unsigned)hi << 32) | (unsigned)lo;
}

// R11: 4 rows/block -> 1024 blocks = 4 blocks/CU = 8 waves/SIMD (R10 at
// 2 blocks/CU was flat at 332us: VALUBusy 62%, still ~38% stall). Same
// 512 threads, 2 codebook entries/thread, dot[4][2]. Per-entry fmaf chain
// identical (c ascending, one accumulator) -> scores bit-identical.
__global__ __launch_bounds__(512)
void rvq_all_k(ushort_t* __restrict__ AH, ushort_t* __restrict__ AL,
               const float* __restrict__ cb, const float* __restrict__ cbT,
               const float* __restrict__ cbn,
               float* __restrict__ codes_out, float* __restrict__ commit)
{
    const int n0 = blockIdx.x * 4;
    const int tid = threadIdx.x;   // 0..511
    __shared__ float res[4][256];
    __shared__ float qacc[4][256];
    __shared__ unsigned long long wred[8][4];
    __shared__ int scode[4];
    __shared__ float ls2[8];
    // stage: res = emb = bf2f(H)+bf2f(L); qacc = 0   (2 floats/thread)
    {
        const int nl = tid >> 7, c2 = (tid & 127) * 2;
        const size_t g = (size_t)(n0 + nl) * 256 + c2;
        const ushort2 h = *(const ushort2*)(AH + g);
        const ushort2 l = *(const ushort2*)(AL + g);
        res[nl][c2 + 0] = bf2f(h.x) + bf2f(l.x);
        res[nl][c2 + 1] = bf2f(h.y) + bf2f(l.y);
        qacc[nl][c2 + 0] = 0.f; qacc[nl][c2 + 1] = 0.f;
    }
    __syncthreads();
    const int wave = tid >> 6, lane = tid & 63;
    float csum = 0.f;
    for (int iq = 0; iq < 8; ++iq) {
        const float* cbq  = cb  + (size_t)iq * 262144;
        const float* cbtp = cbT + (size_t)iq * 262144 + tid * 2;   // 2 entries/thread
        float dot[4][2];
#pragma unroll
        for (int nl = 0; nl < 4; ++nl) { dot[nl][0] = 0.f; dot[nl][1] = 0.f; }
        for (int c = 0; c < 256; c += 4) {
            const float2 w0 = *(const float2*)(cbtp + (size_t)(c + 0) * 1024);
            const float2 w1 = *(const float2*)(cbtp + (size_t)(c + 1) * 1024);
            const float2 w2 = *(const float2*)(cbtp + (size_t)(c + 2) * 1024);
            const float2 w3 = *(const float2*)(cbtp + (size_t)(c + 3) * 1024);
#pragma unroll
            for (int nl = 0; nl < 4; ++nl) {
                const float4 r = *(const float4*)&res[nl][c];
                dot[nl][0] = fmaf(w0.x, r.x, dot[nl][0]);
                dot[nl][0] = fmaf(w1.x, r.y, dot[nl][0]);
                dot[nl][0] = fmaf(w2.x, r.z, dot[nl][0]);
                dot[nl][0] = fmaf(w3.x, r.w, dot[nl][0]);
                dot[nl][1] = fmaf(w0.y, r.x, dot[nl][1]);
                dot[nl][1] = fmaf(w1.y, r.y, dot[nl][1]);
                dot[nl][1] = fmaf(w2.y, r.z, dot[nl][1]);
                dot[nl][1] = fmaf(w3.y, r.w, dot[nl][1]);
            }
        }
        const float2 nrm = *(const float2*)(cbn + iq * 1024 + tid * 2);
#pragma unroll
        for (int nl = 0; nl < 4; ++nl) {
            const float s0 = nrm.x - 2.f * dot[nl][0];
            const float s1 = nrm.y - 2.f * dot[nl][1];
            unsigned long long key =
                ((unsigned long long)ordbits(s0) << 32) | (unsigned)(tid * 2 + 0);
            unsigned long long k1 =
                ((unsigned long long)ordbits(s1) << 32) | (unsigned)(tid * 2 + 1);
            if (k1 < key) key = k1;
            for (int off = 32; off; off >>= 1) {
                unsigned long long o = shfl_xor_u64(key, off);
                if (o < key) key = o;
            }
            if (lane == 0) wred[wave][nl] = key;
        }
        __syncthreads();
        if (tid < 4) {
            unsigned long long bkey = wred[0][tid];
#pragma unroll
            for (int w = 1; w < 8; ++w)
                if (wred[w][tid] < bkey) bkey = wred[w][tid];
            const int code = (int)(bkey & 0xffffffffull);
            scode[tid] = code;
            codes_out[(size_t)(n0 + tid) * 8 + iq] = (float)code;
        }
        __syncthreads();
        // update in LDS: res -= cb[code]; qacc += cb[code]; commit += e^2
#pragma unroll
        for (int rep = 0; rep < 2; ++rep) {
            const int idx = rep * 512 + tid;
            const int nl = idx >> 8, c = idx & 255;
            const int code = scode[nl];
            const float cbv = cbq[(size_t)code * 256 + c];
            const float r = res[nl][c];
            const float e = cbv - r;
            csum = fmaf(e, e, csum);
            res[nl][c] = -e;          // res - cb[code]
            qacc[nl][c] += cbv;
        }
        __syncthreads();
    }
    // commit reduce
    for (int off = 32; off; off >>= 1) csum += __shfl_down(csum, off, 64);
    if (lane == 0) ls2[wave] = csum;
    __syncthreads();
    if (tid == 0) {
        float s = 0.f;
#pragma unroll
        for (int w = 0; w < 8; ++w) s += ls2[w];
        atomicAdd(commit, s);
    }
    // q writeback (split bf16, in place over emb)
    {
        const int nl = tid >> 7, c2 = (tid & 127) * 2;
        const size_t g = (size_t)(n0 + nl) * 256 + c2;
        ushort2 oh, ol;
        fsplit(qacc[nl][c2 + 0], oh.x, ol.x);
        fsplit(qacc[nl][c2 + 1], oh.y, ol.y);
        *(ushort2*)(AH + g) = oh;
        *(ushort2*)(AL + g) = ol;
    }
}

__global__ void commit_write_k(const float* __restrict__ commit, float* __restrict__ out)
{
    out[0] = commit[0] * (1.f / (4096.f * 256.f));
}

// ============================================================================
extern "C" void kernel_launch(void* const* d_in, const int* in_sizes, int n_in,
                              void* d_out, int out_size, void* d_ws, size_t ws_size,
                              hipStream_t stream)
{
    const float* x    = (const float*)d_in[0];
    const float* ed0w = (const float*)d_in[1];
    const float* ed0b = (const float*)d_in[2];
    const float* edw  = (const float*)d_in[3];
    const float* edb  = (const float*)d_in[4];
    const float* erw  = (const float*)d_in[5];
    const float* erb  = (const float*)d_in[6];
    const float* drw  = (const float*)d_in[7];
    const float* drb  = (const float*)d_in[8];
    const float* duw  = (const float*)d_in[9];
    const float* dub  = (const float*)d_in[10];
    const float* dulw = (const float*)d_in[11];
    const float* dulb = (const float*)d_in[12];
    const float* rsum = (const float*)d_in[13];
    const float* rusg = (const float*)d_in[14];
    float* out = (float*)d_out;

    char* base = (char*)d_ws;
    size_t o = 0;
    ushort_t* wH3 = (ushort_t*)(base + o); o += 31457280;   // 80*3*65536 bf16
    ushort_t* wL3 = (ushort_t*)(base + o); o += 31457280;
    ushort_t* w4H = (ushort_t*)(base + o); o += 4194304;    // 8*4*65536 bf16
    ushort_t* w4L = (ushort_t*)(base + o); o += 4194304;
    ushort_t* AH  = (ushort_t*)(base + o); o += 33554432;   // act [2][32768][256]
    ushort_t* AL  = (ushort_t*)(base + o); o += 33554432;
    ushort_t* BH  = (ushort_t*)(base + o); o += 33554432;
    ushort_t* BL  = (ushort_t*)(base + o); o += 33554432;
    float* commit = (float*)(base + o);    o += 64;
    float* cb     = (float*)(base + o);    o += 8388608;    // 8 iq x 1MB
    float* cbT    = (float*)(base + o);    o += 8388608;
    float* cbn    = (float*)(base + o);    o += 32768;

    static const int DIL[4] = {3, 9, 27, 81};

    hipMemsetAsync(commit, 0, 64, stream);

    // weight prep
    wprep3_k<<<20480, 256, 0, stream>>>(erw, drw, wH3, wL3);
    wprep4_k<<<2048, 256, 0, stream>>>(edw, duw, w4H, w4L);

    // conv3 dispatch. R8 ladder (kept): d<=27 one NT notch down at 16384/8192;
    // d=81 ladder unchanged.
    auto conv3 = [&](const ushort_t* iH, const ushort_t* iL,
                     const ushort_t* wh, const ushort_t* wl, const float* bb,
                     const ushort_t* sH, const ushort_t* sL, float alpha,
                     ushort_t* oH, ushort_t* oL, int L, int d) {
        const bool db = (d <= 27);
        if (db) {
            if (L >= 32768)
                convs_k<3, 1, true, 8, 27, true><<<dim3(L / 128, 1, 2), 256, 0, stream>>>(
                    iH, iL, wh, wl, bb, sH, sL, alpha, oH, oL, L, L, d, d);
            else if (L >= 8192)
                convs_k<3, 1, true, 4, 27, true><<<dim3(L / 64, 1, 2), 256, 0, stream>>>(
                    iH, iL, wh, wl, bb, sH, sL, alpha, oH, oL, L, L, d, d);
            else if (L >= 4096)
                convs_k<3, 1, true, 2, 27, true><<<dim3(L / 32, 1, 2), 256, 0, stream>>>(
                    iH, iL, wh, wl, bb, sH, sL, alpha, oH, oL, L, L, d, d);
            else
                convs_k<3, 1, true, 1, 27, true><<<dim3(L / 16, 1, 2), 256, 0, stream>>>(
                    iH, iL, wh, wl, bb, sH, sL, alpha, oH, oL, L, L, d, d);
        } else {
            if (L >= 16384)
                convs_k<3, 1, true, 8, 81, false><<<dim3(L / 128, 1, 2), 256, 0, stream>>>(
                    iH, iL, wh, wl, bb, sH, sL, alpha, oH, oL, L, L, d, d);
            else if (L >= 8192)
                convs_k<3, 1, true, 4, 81, false><<<dim3(L / 64, 1, 2), 256, 0, stream>>>(
                    iH, iL, wh, wl, bb, sH, sL, alpha, oH, oL, L, L, d, d);
            else if (L >= 4096)
                convs_k<3, 1, true, 2, 81, false><<<dim3(L / 32, 1, 2), 256, 0, stream>>>(
                    iH, iL, wh, wl, bb, sH, sL, alpha, oH, oL, L, L, d, d);
            else
                convs_k<3, 1, true, 1, 81, false><<<dim3(L / 16, 1, 2), 256, 0, stream>>>(
                    iH, iL, wh, wl, bb, sH, sL, alpha, oH, oL, L, L, d, d);
        }
    };

    // -------------------- encoder --------------------
    down0_k2<<<dim3(32768, 2), 256, 0, stream>>>(x, ed0w, ed0b, AH, AL);
    int L = 32768;
    for (int i = 0; i < 5; ++i) {
        if (i > 0) {
            const ushort_t* wh = w4H + (size_t)(i - 1) * 262144;
            const ushort_t* wl = w4L + (size_t)(i - 1) * 262144;
            const int Lout = L / 2;
            if (Lout >= 16384)
                convs_k<4, 2, false, 8, 1, false><<<dim3(Lout / 128, 1, 2), 256, 0, stream>>>(
                    AH, AL, wh, wl, edb + (i - 1) * 256, AH, AL, 0.f, BH, BL, L, Lout, 1, 1);
            else if (Lout >= 8192)
                convs_k<4, 2, false, 4, 1, false><<<dim3(Lout / 64, 1, 2), 256, 0, stream>>>(
                    AH, AL, wh, wl, edb + (i - 1) * 256, AH, AL, 0.f, BH, BL, L, Lout, 1, 1);
            else if (Lout >= 4096)
                convs_k<4, 2, false, 2, 1, false><<<dim3(Lout / 32, 1, 2), 256, 0, stream>>>(
                    AH, AL, wh, wl, edb + (i - 1) * 256, AH, AL, 0.f, BH, BL, L, Lout, 1, 1);
            else
                convs_k<4, 2, false, 1, 1, false><<<dim3(Lout / 16, 1, 2), 256, 0, stream>>>(
                    AH, AL, wh, wl, edb + (i - 1) * 256, AH, AL, 0.f, BH, BL, L, Lout, 1, 1);
            ushort_t* t;
            t = AH; AH = BH; BH = t;
            t = AL; AL = BL; BL = t;
            L = Lout;
        }
        for (int j = 0; j < 4; ++j) {
            const int d = DIL[j];
            const size_t u = (size_t)(i * 4 + j) * 2;
            conv3(AH, AL, wH3 + (u + 0) * 196608, wL3 + (u + 0) * 196608,
                  erb + (u + 0) * 256, AH, AL, 0.f, BH, BL, L, d);
            conv3(BH, BL, wH3 + (u + 1) * 196608, wL3 + (u + 1) * 196608,
                  erb + (u + 1) * 256, AH, AL, 1.f, AH, AL, L, 1);
        }
    }

    // -------------------- RVQ (fully fused) --------------------
    rvq_cb_all_k<<<dim3(1024, 8), 256, 0, stream>>>(rsum, rusg, cb, cbT, cbn);
    rvq_all_k<<<1024, 512, 0, stream>>>(AH, AL, cb, cbT, cbn, out + 131072, commit);

    // -------------------- decoder --------------------
    L = 2048;
    for (int i = 0; i < 5; ++i) {
        for (int j = 0; j < 4; ++j) {
            const int d = DIL[j];
            const size_t u = 40 + (size_t)(i * 4 + j) * 2;   // decoder slabs 40..79
            conv3(AH, AL, wH3 + (u + 0) * 196608, wL3 + (u + 0) * 196608,
                  drb + ((size_t)(i * 4 + j) * 2 + 0) * 256, AH, AL, 0.f, BH, BL, L, d);
            conv3(BH, BL, wH3 + (u + 1) * 196608, wL3 + (u + 1) * 196608,
                  drb + ((size_t)(i * 4 + j) * 2 + 1) * 256, AH, AL, 2.f, AH, AL, L, 1);
        }
        if (i < 4) {
            const ushort_t* wh = w4H + (size_t)(4 + i) * 262144;
            const ushort_t* wl = w4L + (size_t)(4 + i) * 262144;
            if (L >= 8192)
                convt_k<4><<<dim3(L / 64, 1, 2), 256, 0, stream>>>(
                    AH, AL, wh, wl, dub + i * 256, BH, BL, L);
            else if (L >= 4096)
                convt_k<2><<<dim3(L / 32, 1, 2), 256, 0, stream>>>(
                    AH, AL, wh, wl, dub + i * 256, BH, BL, L);
            else
                convt_k<1><<<dim3(L / 16, 1, 2), 256, 0, stream>>>(
                    AH, AL, wh, wl, dub + i * 256, BH, BL, L);
            ushort_t* t;
            t = AH; AH = BH; BH = t;
            t = AL; AL = BL; BL = t;
            L *= 2;
        } else {
            uplast_k2<<<dim3(L / 256, 2), 256, 0, stream>>>(AH, AL, dulw, dulb, out, L);
        }
    }

    commit_write_k<<<1, 1, 0, stream>>>(commit, out + 163840);
}

// Round 13
// 4989.402 us; speedup vs baseline: 1.0433x; 1.0433x over previous
//
#include <hip/hip_runtime.h>
#include <cstdint>

#define DEVFN static __device__ __forceinline__
typedef unsigned short ushort_t;
typedef unsigned int uint_t;
typedef short short8 __attribute__((ext_vector_type(8)));
typedef float f32x4 __attribute__((ext_vector_type(4)));

DEVFN float bf2f(ushort_t h) { return __uint_as_float(((uint_t)h) << 16); }
DEVFN ushort_t bfhi(float f) {
    uint_t u = __float_as_uint(f);
    u += 0x7fffu + ((u >> 16) & 1u);
    return (ushort_t)(u >> 16);
}
DEVFN void fsplit(float f, ushort_t& h, ushort_t& l) {
    h = bfhi(f);
    l = bfhi(f - bf2f(h));
}
// relu on a packed pair of bf16 hi/lo dwords (2 elements each)
// R13: restored exact R10 form (R12's revert mistyped the l-mask for f0,
// folding to 0 and corrupting element 1 -> absmax 91136 failure).
DEVFN void relu_pair(uint_t& h, uint_t& l) {
    float f0 = bf2f((ushort_t)(h & 0xffffu)) + bf2f((ushort_t)(l & 0xffffu));
    float f1 = bf2f((ushort_t)(h >> 16)) + bf2f((ushort_t)(l >> 16));
    if (f0 <= 0.f) { h &= 0xffff0000u; l &= 0xffff0000u; }
    if (f1 <= 0.f) { h &= 0x0000ffffu; l &= 0x0000ffffu; }
}
// XCD chunked swizzle (T1) — adjacent t-tiles to the same XCD L2.
// VERIFIED R5: FETCH 145->37 MB on L=32768 convs. Bijective iff gx%8==0.
DEVFN int xcd_swz(int bx, int gx) {
    return ((gx & 7) == 0) ? ((bx & 7) * (gx >> 3) + (bx >> 3)) : bx;
}

// ============================================================================
// weight prep: fp32 [co][ci][k] -> bf16 hi/lo [tap][co][ci]
// ============================================================================
__global__ __launch_bounds__(256)
void wprep3_k(const float* __restrict__ erw, const float* __restrict__ drw,
              ushort_t* __restrict__ wH, ushort_t* __restrict__ wL)
{
    const int gid = blockIdx.x * 256 + threadIdx.x;   // 80*65536 threads
    const int conv = gid >> 16;
    const int rem  = gid & 65535;                      // co*256+ci
    const int co = rem >> 8, ci = rem & 255;
    const float* src = (conv < 40) ? (erw + (size_t)conv * 196608)
                                   : (drw + (size_t)(conv - 40) * 196608);
    const float* p = src + ((size_t)co * 256 + ci) * 3;
    ushort_t* oh = wH + (size_t)conv * 196608 + rem;
    ushort_t* ol = wL + (size_t)conv * 196608 + rem;
#pragma unroll
    for (int k = 0; k < 3; ++k) {
        ushort_t h, l; fsplit(p[k], h, l);
        oh[k * 65536] = h; ol[k * 65536] = l;
    }
}

__global__ __launch_bounds__(256)
void wprep4_k(const float* __restrict__ edw, const float* __restrict__ duw,
              ushort_t* __restrict__ wH, ushort_t* __restrict__ wL)
{
    const int gid = blockIdx.x * 256 + threadIdx.x;   // 8*65536 threads
    const int conv = gid >> 16;
    const int rem  = gid & 65535;
    const int co = rem >> 8, ci = rem & 255;
    ushort_t* oh = wH + (size_t)conv * 262144 + rem;
    ushort_t* ol = wL + (size_t)conv * 262144 + rem;
#pragma unroll
    for (int k = 0; k < 4; ++k) {
        float f;
        if (conv < 4)  f = edw[(size_t)conv * 262144 + ((size_t)co * 256 + ci) * 4 + k];
        else           f = duw[(size_t)(conv - 4) * 262144 + ((size_t)ci * 256 + co) * 4 + k];
        ushort_t h, l; fsplit(f, h, l);
        oh[k * 65536] = h; ol[k * 65536] = l;
    }
}

// ============================================================================
// split-precision MFMA conv.
// act layout [b][t][256c] bf16 hi/lo. Block: NT*16 t x 256 co, 4 waves x 64co.
// (R8/R9/R10-verified: T1 XCD swizzle, DBUF prefetch d<=27, T5 setprio,
// paired epilogue.)
// ============================================================================
template<int TAPS, int STRIDE, bool RELU, int NT, int DMAX, bool DBUF>
__global__ __launch_bounds__(256, (NT >= 8) ? 2 : 3)
void convs_k(const ushort_t* __restrict__ inH, const ushort_t* __restrict__ inL,
             const ushort_t* __restrict__ wH, const ushort_t* __restrict__ wL,
             const float* __restrict__ bias,
             const ushort_t* __restrict__ srcH, const ushort_t* __restrict__ srcL,
             float alpha,
             ushort_t* __restrict__ outH, ushort_t* __restrict__ outL,
             int Lin, int Lout, int dil, int pad)
{
    constexpr int ROWS = NT * 16;
    constexpr int SMAX = STRIDE * (ROWS - 1) + (TAPS - 1) * DMAX + 1;
    constexpr int XSB  = SMAX * 80;          // bytes per plane per buffer
    constexpr int NEED = DBUF ? 4 * XSB : 2 * XSB;
    constexpr int EMIN = (NT >= 2) ? 33280 : 16640;   // epilogue rows x 260 x 4B
    constexpr int ARENA = (NEED > EMIN) ? NEED : EMIN;
    static_assert(!DBUF || (4 * SMAX <= TAPS * 256), "prefetch item budget");
    __shared__ __align__(16) char sarena[ARENA];

    const int tid = threadIdx.x;
    const int b = blockIdx.z;
    const int t0 = xcd_swz(blockIdx.x, gridDim.x) * ROWS;
    const int wave = tid >> 6, lane = tid & 63;
    const int quad = lane >> 4, lr = lane & 15;
    const int cow = wave * 64;
    const size_t inbase = (size_t)b * Lin * 256;
    const int S = STRIDE * (ROWS - 1) + (TAPS - 1) * dil + 1;
    const int g0 = STRIDE * t0 - pad;

    f32x4 acc[4][NT];
#pragma unroll
    for (int m = 0; m < 4; ++m)
#pragma unroll
        for (int n = 0; n < NT; ++n) acc[m][n] = (f32x4)0.f;

    if constexpr (DBUF) {
        ushort_t (*xsH0)[40] = (ushort_t(*)[40])(sarena);
        ushort_t (*xsL0)[40] = (ushort_t(*)[40])(sarena + XSB);
        ushort_t (*xsH1)[40] = (ushort_t(*)[40])(sarena + 2 * XSB);
        ushort_t (*xsL1)[40] = (ushort_t(*)[40])(sarena + 3 * XSB);
        // ---- prologue: stage chunk 0 into buffer 0 ----
        for (int idx = tid; idx < S * 4; idx += 256) {
            const int s = idx >> 2, p = idx & 3;
            const int t = g0 + s;
            uint4 hv = make_uint4(0, 0, 0, 0), lv = hv;
            if (t >= 0 && t < Lin) {
                const size_t g = inbase + (size_t)t * 256 + p * 8;
                hv = *(const uint4*)(inH + g);
                lv = *(const uint4*)(inL + g);
                if (RELU) {
                    relu_pair(hv.x, lv.x); relu_pair(hv.y, lv.y);
                    relu_pair(hv.z, lv.z); relu_pair(hv.w, lv.w);
                }
            }
            *(uint4*)&xsH0[s][p * 8] = hv;
            *(uint4*)&xsL0[s][p * 8] = lv;
        }
        __syncthreads();
        for (int chunk = 0; chunk < 8; ++chunk) {
            const int ci0 = chunk * 32;
            ushort_t (*xsH)[40] = (chunk & 1) ? xsH1 : xsH0;
            ushort_t (*xsL)[40] = (chunk & 1) ? xsL1 : xsL0;
            ushort_t (*xnH)[40] = (chunk & 1) ? xsH0 : xsH1;
            ushort_t (*xnL)[40] = (chunk & 1) ? xsL0 : xsL1;
            const bool pf = (chunk < 7);
#pragma unroll
            for (int tap = 0; tap < TAPS; ++tap) {
                // A fragments FIRST (their waitcnt shouldn't drain prefetch)
                const ushort_t* wHt = wH + (size_t)tap * 65536 + ci0 + quad * 8;
                const ushort_t* wLt = wL + (size_t)tap * 65536 + ci0 + quad * 8;
                short8 aH[4], aL[4];
#pragma unroll
                for (int m = 0; m < 4; ++m) {
                    const int co = cow + m * 16 + lr;
                    aH[m] = *(const short8*)(wHt + co * 256);
                    aL[m] = *(const short8*)(wLt + co * 256);
                }
                // issue next-chunk prefetch (this tap's item slice)
                const int idx = tap * 256 + tid;
                const int s = idx >> 2, p = idx & 3;
                const int tr = g0 + s;
                const bool inr = (idx < S * 4);
                uint4 hv = make_uint4(0, 0, 0, 0), lv = hv;
                if (pf && inr && tr >= 0 && tr < Lin) {
                    const size_t g = inbase + (size_t)tr * 256 + (ci0 + 32) + p * 8;
                    hv = *(const uint4*)(inH + g);
                    lv = *(const uint4*)(inL + g);
                }
                // compute this tap (hides prefetch latency)
                const int rb = tap * dil;
                __builtin_amdgcn_s_setprio(1);
#pragma unroll
                for (int n = 0; n < NT; ++n) {
                    const int srow = STRIDE * (n * 16 + lr) + rb;
                    const short8 bH = *(const short8*)&xsH[srow][quad * 8];
                    const short8 bL = *(const short8*)&xsL[srow][quad * 8];
#pragma unroll
                    for (int m = 0; m < 4; ++m)
                        acc[m][n] = __builtin_amdgcn_mfma_f32_16x16x32_bf16(aH[m], bH, acc[m][n], 0, 0, 0);
#pragma unroll
                    for (int m = 0; m < 4; ++m)
                        acc[m][n] = __builtin_amdgcn_mfma_f32_16x16x32_bf16(aH[m], bL, acc[m][n], 0, 0, 0);
#pragma unroll
                    for (int m = 0; m < 4; ++m)
                        acc[m][n] = __builtin_amdgcn_mfma_f32_16x16x32_bf16(aL[m], bH, acc[m][n], 0, 0, 0);
                }
                __builtin_amdgcn_s_setprio(0);
                // land prefetched data in the other buffer
                if (pf && inr) {
                    if (RELU) {
                        relu_pair(hv.x, lv.x); relu_pair(hv.y, lv.y);
                        relu_pair(hv.z, lv.z); relu_pair(hv.w, lv.w);
                    }
                    *(uint4*)&xnH[s][p * 8] = hv;
                    *(uint4*)&xnL[s][p * 8] = lv;
                }
            }
            __syncthreads();   // one barrier per chunk
        }
    } else {
        // ---- single-buffer path (d=81, conv4) ----
        ushort_t (*xsH)[40] = (ushort_t(*)[40])(sarena);
        ushort_t (*xsL)[40] = (ushort_t(*)[40])(sarena + XSB);
        for (int chunk = 0; chunk < 8; ++chunk) {
            const int ci0 = chunk * 32;
            __syncthreads();
            for (int idx = tid; idx < S * 4; idx += 256) {
                const int s = idx >> 2, p = idx & 3;
                const int t = g0 + s;
                uint4 hv = make_uint4(0, 0, 0, 0), lv = hv;
                if (t >= 0 && t < Lin) {
                    const size_t g = inbase + (size_t)t * 256 + ci0 + p * 8;
                    hv = *(const uint4*)(inH + g);
                    lv = *(const uint4*)(inL + g);
                    if (RELU) {
                        relu_pair(hv.x, lv.x); relu_pair(hv.y, lv.y);
                        relu_pair(hv.z, lv.z); relu_pair(hv.w, lv.w);
                    }
                }
                *(uint4*)&xsH[s][p * 8] = hv;
                *(uint4*)&xsL[s][p * 8] = lv;
            }
            __syncthreads();
#pragma unroll
            for (int tap = 0; tap < TAPS; ++tap) {
                const ushort_t* wHt = wH + (size_t)tap * 65536 + ci0 + quad * 8;
                const ushort_t* wLt = wL + (size_t)tap * 65536 + ci0 + quad * 8;
                short8 aH[4], aL[4];
#pragma unroll
                for (int m = 0; m < 4; ++m) {
                    const int co = cow + m * 16 + lr;
                    aH[m] = *(const short8*)(wHt + co * 256);
                    aL[m] = *(const short8*)(wLt + co * 256);
                }
                const int rb = tap * dil;
                __builtin_amdgcn_s_setprio(1);
#pragma unroll
                for (int n = 0; n < NT; ++n) {
                    const int srow = STRIDE * (n * 16 + lr) + rb;
                    const short8 bH = *(const short8*)&xsH[srow][quad * 8];
                    const short8 bL = *(const short8*)&xsL[srow][quad * 8];
#pragma unroll
                    for (int m = 0; m < 4; ++m)
                        acc[m][n] = __builtin_amdgcn_mfma_f32_16x16x32_bf16(aH[m], bH, acc[m][n], 0, 0, 0);
#pragma unroll
                    for (int m = 0; m < 4; ++m)
                        acc[m][n] = __builtin_amdgcn_mfma_f32_16x16x32_bf16(aH[m], bL, acc[m][n], 0, 0, 0);
#pragma unroll
                    for (int m = 0; m < 4; ++m)
                        acc[m][n] = __builtin_amdgcn_mfma_f32_16x16x32_bf16(aL[m], bH, acc[m][n], 0, 0, 0);
                }
                __builtin_amdgcn_s_setprio(0);
            }
        }
    }
    // ---- coalesced epilogue ----
    float4 bvv[4];
#pragma unroll
    for (int m = 0; m < 4; ++m)
        bvv[m] = *(const float4*)&bias[cow + m * 16 + quad * 4];
    __syncthreads();
    if constexpr (NT >= 2) {
        // paired n-groups -> 32-row ebuf, half the barriers (unrolled: rule #20)
        float (*ebuf)[260] = (float(*)[260])sarena;   // 32 rows x 260 cols
#pragma unroll
        for (int n2 = 0; n2 < NT; n2 += 2) {
#pragma unroll
            for (int half = 0; half < 2; ++half) {
                const int n = n2 + half;
#pragma unroll
                for (int m = 0; m < 4; ++m) {
                    float4 v;
                    v.x = acc[m][n][0] + bvv[m].x;
                    v.y = acc[m][n][1] + bvv[m].y;
                    v.z = acc[m][n][2] + bvv[m].z;
                    v.w = acc[m][n][3] + bvv[m].w;
                    *(float4*)&ebuf[16 * half + lr][cow + m * 16 + quad * 4] = v;
                }
            }
            __syncthreads();
#pragma unroll
            for (int h = 0; h < 8; ++h) {
                const int row = (tid >> 4) + 16 * (h >> 2);
                const int col = (tid & 15) * 4 + (h & 3) * 64;
                const int t = t0 + n2 * 16 + row;
                const size_t gr = ((size_t)b * Lout + t) * 256;
                float4 v = *(const float4*)&ebuf[row][col];
                if (alpha != 0.f) {
                    const ushort4 sh = *(const ushort4*)(srcH + gr + col);
                    const ushort4 sl = *(const ushort4*)(srcL + gr + col);
                    v.x += alpha * (bf2f(sh.x) + bf2f(sl.x));
                    v.y += alpha * (bf2f(sh.y) + bf2f(sl.y));
                    v.z += alpha * (bf2f(sh.z) + bf2f(sl.z));
                    v.w += alpha * (bf2f(sh.w) + bf2f(sl.w));
                }
                ushort4 oh, ol;
                fsplit(v.x, oh.x, ol.x); fsplit(v.y, oh.y, ol.y);
                fsplit(v.z, oh.z, ol.z); fsplit(v.w, oh.w, ol.w);
                *(ushort4*)(outH + gr + col) = oh;
                *(ushort4*)(outL + gr + col) = ol;
            }
            __syncthreads();
        }
    } else {
        float (*ebuf)[260] = (float(*)[260])sarena;   // 16 rows x 260 cols
#pragma unroll
        for (int n = 0; n < NT; ++n) {
#pragma unroll
            for (int m = 0; m < 4; ++m) {
                float4 v;
                v.x = acc[m][n][0] + bvv[m].x;
                v.y = acc[m][n][1] + bvv[m].y;
                v.z = acc[m][n][2] + bvv[m].z;
                v.w = acc[m][n][3] + bvv[m].w;
                *(float4*)&ebuf[lr][cow + m * 16 + quad * 4] = v;
            }
            __syncthreads();
            {
                const int row = tid >> 4;
                const int c00 = (tid & 15) * 4;
                const int t = t0 + n * 16 + row;
                const size_t gr = ((size_t)b * Lout + t) * 256;
#pragma unroll
                for (int rep = 0; rep < 4; ++rep) {
                    const int col = c00 + rep * 64;
                    float4 v = *(const float4*)&ebuf[row][col];
                    if (alpha != 0.f) {
                        const ushort4 sh = *(const ushort4*)(srcH + gr + col);
                        const ushort4 sl = *(const ushort4*)(srcL + gr + col);
                        v.x += alpha * (bf2f(sh.x) + bf2f(sl.x));
                        v.y += alpha * (bf2f(sh.y) + bf2f(sl.y));
                        v.z += alpha * (bf2f(sh.z) + bf2f(sl.z));
                        v.w += alpha * (bf2f(sh.w) + bf2f(sl.w));
                    }
                    ushort4 oh, ol;
                    fsplit(v.x, oh.x, ol.x); fsplit(v.y, oh.y, ol.y);
                    fsplit(v.z, oh.z, ol.z); fsplit(v.w, oh.w, ol.w);
                    *(ushort4*)(outH + gr + col) = oh;
                    *(ushort4*)(outL + gr + col) = ol;
                }
            }
            __syncthreads();
        }
    }
}

// ============================================================================
// conv transpose k=4 s=2 p=1 (split MFMA). Block: NTc*16 input m x 256 co.
// out[2m]   = x[m]w1 + x[m-1]w3 ; out[2m+1] = x[m+1]w0 + x[m]w2
// (R10 verbatim)
// ============================================================================
template<int NTc>
__global__ __launch_bounds__(256, 2)
void convt_k(const ushort_t* __restrict__ inH, const ushort_t* __restrict__ inL,
             const ushort_t* __restrict__ wH, const ushort_t* __restrict__ wL,
             const float* __restrict__ bias,
             ushort_t* __restrict__ outH, ushort_t* __restrict__ outL, int Lin)
{
    constexpr int ROWS = NTc * 16;
    constexpr int S = ROWS + 2;
    constexpr int XSB = S * 40 * 2;
    constexpr int ARENA = (2 * XSB > 33280) ? 2 * XSB : 33280;
    __shared__ __align__(16) char sarena[ARENA];
    ushort_t (*xsH)[40] = (ushort_t(*)[40])(sarena);
    ushort_t (*xsL)[40] = (ushort_t(*)[40])(sarena + XSB);

    const int tid = threadIdx.x;
    const int b = blockIdx.z;
    const int m0 = xcd_swz(blockIdx.x, gridDim.x) * ROWS;
    const int Lout = Lin * 2;
    const int wave = tid >> 6, lane = tid & 63;
    const int quad = lane >> 4, lr = lane & 15;
    const int cow = wave * 64;
    const size_t inbase = (size_t)b * Lin * 256;

    f32x4 acc[4][NTc][2];
#pragma unroll
    for (int m = 0; m < 4; ++m)
#pragma unroll
        for (int n = 0; n < NTc; ++n) { acc[m][n][0] = (f32x4)0.f; acc[m][n][1] = (f32x4)0.f; }

    for (int chunk = 0; chunk < 8; ++chunk) {
        const int ci0 = chunk * 32;
        __syncthreads();
        for (int idx = tid; idx < S * 4; idx += 256) {
            const int s = idx >> 2, p = idx & 3;
            const int t = m0 - 1 + s;
            uint4 hv = make_uint4(0, 0, 0, 0), lv = hv;
            if (t >= 0 && t < Lin) {
                const size_t g = inbase + (size_t)t * 256 + ci0 + p * 8;
                hv = *(const uint4*)(inH + g);
                lv = *(const uint4*)(inL + g);
            }
            *(uint4*)&xsH[s][p * 8] = hv;
            *(uint4*)&xsL[s][p * 8] = lv;
        }
        __syncthreads();
#pragma unroll
        for (int tap = 0; tap < 4; ++tap) {
            const int ph = (tap == 0 || tap == 2) ? 1 : 0;   // PHASE = {1,0,1,0}
            const int sh = (tap == 0) ? 1 : ((tap == 3) ? -1 : 0);  // SHIFT
            const ushort_t* wHt = wH + (size_t)tap * 65536 + ci0 + quad * 8;
            const ushort_t* wLt = wL + (size_t)tap * 65536 + ci0 + quad * 8;
            short8 aH[4], aL[4];
#pragma unroll
            for (int m = 0; m < 4; ++m) {
                const int co = cow + m * 16 + lr;
                aH[m] = *(const short8*)(wHt + co * 256);
                aL[m] = *(const short8*)(wLt + co * 256);
            }
            __builtin_amdgcn_s_setprio(1);
#pragma unroll
            for (int n = 0; n < NTc; ++n) {
                const int srow = n * 16 + lr + sh + 1;
                const short8 bH = *(const short8*)&xsH[srow][quad * 8];
                const short8 bL = *(const short8*)&xsL[srow][quad * 8];
#pragma unroll
                for (int m = 0; m < 4; ++m)
                    acc[m][n][ph] = __builtin_amdgcn_mfma_f32_16x16x32_bf16(aH[m], bH, acc[m][n][ph], 0, 0, 0);
#pragma unroll
                for (int m = 0; m < 4; ++m)
                    acc[m][n][ph] = __builtin_amdgcn_mfma_f32_16x16x32_bf16(aH[m], bL, acc[m][n][ph], 0, 0, 0);
#pragma unroll
                for (int m = 0; m < 4; ++m)
                    acc[m][n][ph] = __builtin_amdgcn_mfma_f32_16x16x32_bf16(aL[m], bH, acc[m][n][ph], 0, 0, 0);
            }
            __builtin_amdgcn_s_setprio(0);
        }
    }
    // ---- coalesced epilogue: 32 output rows per n-group ----
    float4 bvv[4];
#pragma unroll
    for (int m = 0; m < 4; ++m)
        bvv[m] = *(const float4*)&bias[cow + m * 16 + quad * 4];
    __syncthreads();
    float (*ebuf)[260] = (float(*)[260])sarena;   // 32 rows x 260 cols
#pragma unroll
    for (int n = 0; n < NTc; ++n) {
#pragma unroll
        for (int m = 0; m < 4; ++m) {
#pragma unroll
            for (int ph = 0; ph < 2; ++ph) {
                float4 v;
                v.x = acc[m][n][ph][0] + bvv[m].x;
                v.y = acc[m][n][ph][1] + bvv[m].y;
                v.z = acc[m][n][ph][2] + bvv[m].z;
                v.w = acc[m][n][ph][3] + bvv[m].w;
                *(float4*)&ebuf[2 * lr + ph][cow + m * 16 + quad * 4] = v;
            }
        }
        __syncthreads();
        {
            const int baset = 2 * (m0 + n * 16);
#pragma unroll
            for (int h = 0; h < 8; ++h) {
                const int row = (tid >> 4) + 16 * (h >> 2);
                const int col = (tid & 15) * 4 + (h & 3) * 64;
                const int t = baset + row;
                const size_t gr = ((size_t)b * Lout + t) * 256 + col;
                float4 v = *(const float4*)&ebuf[row][col];
                ushort4 oh, ol;
                fsplit(v.x, oh.x, ol.x); fsplit(v.y, oh.y, ol.y);
                fsplit(v.z, oh.z, ol.z); fsplit(v.w, oh.w, ol.w);
                *(ushort4*)(outH + gr) = oh;
                *(ushort4*)(outL + gr) = ol;
            }
        }
        __syncthreads();
    }
}

// ============================================================================
// first conv 1->256 k=4 s=2 p=1 ; writes [b][t][c] hi/lo
// ============================================================================
__global__ __launch_bounds__(256)
void down0_k2(const float* __restrict__ x, const float* __restrict__ w,
              const float* __restrict__ bias,
              ushort_t* __restrict__ outH, ushort_t* __restrict__ outL)
{
    const int t = blockIdx.x;               // 32768
    const int b = blockIdx.y;
    const int co = threadIdx.x;
    const float* xb = x + (size_t)b * 65536;
    const float4 wv = *(const float4*)(w + co * 4);
    float s = bias[co];
    const int ti0 = 2 * t - 1;
    if (ti0 >= 0)      s = fmaf(xb[ti0], wv.x, s);
    s = fmaf(xb[ti0 + 1], wv.y, s);
    s = fmaf(xb[ti0 + 2], wv.z, s);
    if (ti0 + 3 < 65536) s = fmaf(xb[ti0 + 3], wv.w, s);
    ushort_t h, l; fsplit(s, h, l);
    const size_t g = ((size_t)b * 32768 + t) * 256 + co;
    outH[g] = h; outL[g] = l;
}

// ============================================================================
// last conv transpose 256->1
// ============================================================================
__global__ __launch_bounds__(256)
void uplast_k2(const ushort_t* __restrict__ inH, const ushort_t* __restrict__ inL,
               const float* __restrict__ w, const float* __restrict__ bias,
               float* __restrict__ out, int Lin)
{
    const int m = blockIdx.x * 256 + threadIdx.x;
    const int b = blockIdx.y;
    const float bv = bias[0];
    float aE = bv, aO = bv;
    const size_t base = (size_t)b * Lin * 256;
    const ushort_t* r0H = inH + base + (size_t)m * 256;
    const ushort_t* r0L = inL + base + (size_t)m * 256;
    const bool hasM = (m > 0), hasP = (m + 1 < Lin);
    for (int c0 = 0; c0 < 256; c0 += 8) {
        uint4 h0 = *(const uint4*)(r0H + c0);
        uint4 l0 = *(const uint4*)(r0L + c0);
        uint4 hm = make_uint4(0,0,0,0), lm = hm, hp = hm, lp = hm;
        if (hasM) { hm = *(const uint4*)(r0H - 256 + c0); lm = *(const uint4*)(r0L - 256 + c0); }
        if (hasP) { hp = *(const uint4*)(r0H + 256 + c0); lp = *(const uint4*)(r0L + 256 + c0); }
        const uint_t* h0p = (const uint_t*)&h0; const uint_t* l0p = (const uint_t*)&l0;
        const uint_t* hmp = (const uint_t*)&hm; const uint_t* lmp = (const uint_t*)&lm;
        const uint_t* hpp = (const uint_t*)&hp; const uint_t* lpp = (const uint_t*)&lp;
#pragma unroll
        for (int e = 0; e < 4; ++e) {
#pragma unroll
            for (int half = 0; half < 2; ++half) {
                const int sh = half * 16;
                const int ci = c0 + e * 2 + half;
                const float x0  = bf2f((ushort_t)(h0p[e] >> sh)) + bf2f((ushort_t)(l0p[e] >> sh));
                const float xm1 = bf2f((ushort_t)(hmp[e] >> sh)) + bf2f((ushort_t)(lmp[e] >> sh));
                const float xp1 = bf2f((ushort_t)(hpp[e] >> sh)) + bf2f((ushort_t)(lpp[e] >> sh));
                const float4 wv = *(const float4*)(w + ci * 4);
                aE = fmaf(x0, wv.y, fmaf(xm1, wv.w, aE));
                aO = fmaf(xp1, wv.x, fmaf(x0, wv.z, aO));
            }
        }
    }
    *(float2*)(out + (size_t)b * 2 * Lin + 2 * m) = make_float2(aE, aO);
}

// ============================================================================
// RVQ (fp32)
// ============================================================================
// all 8 codebooks in ONE dispatch
__global__ __launch_bounds__(256)
void rvq_cb_all_k(const float* __restrict__ sum, const float* __restrict__ usage,
                  float* __restrict__ cb, float* __restrict__ cbT,
                  float* __restrict__ cbn)
{
    const int k = blockIdx.x, iq = blockIdx.y, c = threadIdx.x;
    const float den = fmaxf(usage[iq * 1024 + k], 1e-5f);
    const float v = sum[((size_t)iq * 1024 + k) * 256 + c] / den;
    cb[(size_t)iq * 262144 + (size_t)k * 256 + c] = v;
    cbT[(size_t)iq * 262144 + (size_t)c * 1024 + k] = v;
    float s = v * v;
    for (int off = 32; off; off >>= 1) s += __shfl_down(s, off, 64);
    __shared__ float ls[4];
    if ((c & 63) == 0) ls[c >> 6] = s;
    __syncthreads();
    if (c == 0) cbn[iq * 1024 + k] = ls[0] + ls[1] + ls[2] + ls[3];
}

DEVFN unsigned int ordbits(float f)
{
    unsigned u = __float_as_uint(f);
    return (u & 0x80000000u) ? ~u : (u | 0x80000000u);
}
DEVFN unsigned long long shfl_xor_u64(unsigned long long v, int mask)
{
    int lo = (int)(v & 0xffffffffull), hi = (int)(v >> 32);
    lo = __shfl_xor(lo, mask, 64);
    hi = __shfl_xor(hi, mask, 64);
    return ((unsigned long long)(unsigned)hi << 32) | (unsigned)lo;
}

// R10 config (verified optimum). 8 rows/block x 512 blocks = 2 blk/CU.
// R11's 1024-block variant regressed (FETCH 36->126 MB: codebook re-read
// traffic exceeds L2/L3 past 512 blocks). Measured balance point.
__global__ __launch_bounds__(512)
void rvq_all_k(ushort_t* __restrict__ AH, ushort_t* __restrict__ AL,
               const float* __restrict__ cb, const float* __restrict__ cbT,
               const float* __restrict__ cbn,
               float* __restrict__ codes_out, float* __restrict__ commit)
{
    const int n0 = blockIdx.x * 8;
    const int tid = threadIdx.x;   // 0..511
    __shared__ float res[8][256];
    __shared__ float qacc[8][256];
    __shared__ unsigned long long wred[8][8];
    __shared__ int scode[8];
    __shared__ float ls2[8];
    // stage: res = emb = bf2f(H)+bf2f(L); qacc = 0   (512 items, one pass)
    {
        const int nl = tid >> 6, c4 = (tid & 63) * 4;
        const size_t g = (size_t)(n0 + nl) * 256 + c4;
        const ushort4 h = *(const ushort4*)(AH + g);
        const ushort4 l = *(const ushort4*)(AL + g);
        res[nl][c4 + 0] = bf2f(h.x) + bf2f(l.x);
        res[nl][c4 + 1] = bf2f(h.y) + bf2f(l.y);
        res[nl][c4 + 2] = bf2f(h.z) + bf2f(l.z);
        res[nl][c4 + 3] = bf2f(h.w) + bf2f(l.w);
        qacc[nl][c4 + 0] = 0.f; qacc[nl][c4 + 1] = 0.f;
        qacc[nl][c4 + 2] = 0.f; qacc[nl][c4 + 3] = 0.f;
    }
    __syncthreads();
    const int wave = tid >> 6, lane = tid & 63;
    float csum = 0.f;
    for (int iq = 0; iq < 8; ++iq) {
        const float* cbq  = cb  + (size_t)iq * 262144;
        const float* cbtp = cbT + (size_t)iq * 262144 + tid * 2;   // 2 entries/thread
        float dot[8][2];
#pragma unroll
        for (int nl = 0; nl < 8; ++nl) { dot[nl][0] = 0.f; dot[nl][1] = 0.f; }
        for (int c = 0; c < 256; c += 4) {
            const float2 w0 = *(const float2*)(cbtp + (size_t)(c + 0) * 1024);
            const float2 w1 = *(const float2*)(cbtp + (size_t)(c + 1) * 1024);
            const float2 w2 = *(const float2*)(cbtp + (size_t)(c + 2) * 1024);
            const float2 w3 = *(const float2*)(cbtp + (size_t)(c + 3) * 1024);
#pragma unroll
            for (int nl = 0; nl < 8; ++nl) {
                const float4 r = *(const float4*)&res[nl][c];
                dot[nl][0] = fmaf(w0.x, r.x, dot[nl][0]);
                dot[nl][0] = fmaf(w1.x, r.y, dot[nl][0]);
                dot[nl][0] = fmaf(w2.x, r.z, dot[nl][0]);
                dot[nl][0] = fmaf(w3.x, r.w, dot[nl][0]);
                dot[nl][1] = fmaf(w0.y, r.x, dot[nl][1]);
                dot[nl][1] = fmaf(w1.y, r.y, dot[nl][1]);
                dot[nl][1] = fmaf(w2.y, r.z, dot[nl][1]);
                dot[nl][1] = fmaf(w3.y, r.w, dot[nl][1]);
            }
        }
        const float2 nrm = *(const float2*)(cbn + iq * 1024 + tid * 2);
#pragma unroll
        for (int nl = 0; nl < 8; ++nl) {
            const float s0 = nrm.x - 2.f * dot[nl][0];
            const float s1 = nrm.y - 2.f * dot[nl][1];
            unsigned long long key =
                ((unsigned long long)ordbits(s0) << 32) | (unsigned)(tid * 2 + 0);
            unsigned long long k1 =
                ((unsigned long long)ordbits(s1) << 32) | (unsigned)(tid * 2 + 1);
            if (k1 < key) key = k1;
            for (int off = 32; off; off >>= 1) {
                unsigned long long o = shfl_xor_u64(key, off);
                if (o < key) key = o;
            }
            if (lane == 0) wred[wave][nl] = key;
        }
        __syncthreads();
        if (tid < 8) {
            unsigned long long bkey = wred[0][tid];
#pragma unroll
            for (int w = 1; w < 8; ++w)
                if (wred[w][tid] < bkey) bkey = wred[w][tid];
            const int code = (int)(bkey & 0xffffffffull);
            scode[tid] = code;
            codes_out[(size_t)(n0 + tid) * 8 + iq] = (float)code;
        }
        __syncthreads();
        // update in LDS: res -= cb[code]; qacc += cb[code]; commit += e^2
#pragma unroll
        for (int rep = 0; rep < 4; ++rep) {
            const int idx = rep * 512 + tid;
            const int nl = idx >> 8, c = idx & 255;
            const int code = scode[nl];
            const float cbv = cbq[(size_t)code * 256 + c];
            const float r = res[nl][c];
            const float e = cbv - r;
            csum = fmaf(e, e, csum);
            res[nl][c] = -e;          // res - cb[code]
            qacc[nl][c] += cbv;
        }
        __syncthreads();
    }
    // commit reduce
    for (int off = 32; off; off >>= 1) csum += __shfl_down(csum, off, 64);
    if (lane == 0) ls2[wave] = csum;
    __syncthreads();
    if (tid == 0) {
        float s = 0.f;
#pragma unroll
        for (int w = 0; w < 8; ++w) s += ls2[w];
        atomicAdd(commit, s);
    }
    // q writeback (split bf16, in place over emb)
    {
        const int nl = tid >> 6, c4 = (tid & 63) * 4;
        const size_t g = (size_t)(n0 + nl) * 256 + c4;
        ushort4 oh, ol;
        fsplit(qacc[nl][c4 + 0], oh.x, ol.x);
        fsplit(qacc[nl][c4 + 1], oh.y, ol.y);
        fsplit(qacc[nl][c4 + 2], oh.z, ol.z);
        fsplit(qacc[nl][c4 + 3], oh.w, ol.w);
        *(ushort4*)(AH + g) = oh;
        *(ushort4*)(AL + g) = ol;
    }
}

__global__ void commit_write_k(const float* __restrict__ commit, float* __restrict__ out)
{
    out[0] = commit[0] * (1.f / (4096.f * 256.f));
}

// ============================================================================
extern "C" void kernel_launch(void* const* d_in, const int* in_sizes, int n_in,
                              void* d_out, int out_size, void* d_ws, size_t ws_size,
                              hipStream_t stream)
{
    const float* x    = (const float*)d_in[0];
    const float* ed0w = (const float*)d_in[1];
    const float* ed0b = (const float*)d_in[2];
    const float* edw  = (const float*)d_in[3];
    const float* edb  = (const float*)d_in[4];
    const float* erw  = (const float*)d_in[5];
    const float* erb  = (const float*)d_in[6];
    const float* drw  = (const float*)d_in[7];
    const float* drb  = (const float*)d_in[8];
    const float* duw  = (const float*)d_in[9];
    const float* dub  = (const float*)d_in[10];
    const float* dulw = (const float*)d_in[11];
    const float* dulb = (const float*)d_in[12];
    const float* rsum = (const float*)d_in[13];
    const float* rusg = (const float*)d_in[14];
    float* out = (float*)d_out;

    char* base = (char*)d_ws;
    size_t o = 0;
    ushort_t* wH3 = (ushort_t*)(base + o); o += 31457280;   // 80*3*65536 bf16
    ushort_t* wL3 = (ushort_t*)(base + o); o += 31457280;
    ushort_t* w4H = (ushort_t*)(base + o); o += 4194304;    // 8*4*65536 bf16
    ushort_t* w4L = (ushort_t*)(base + o); o += 4194304;
    ushort_t* AH  = (ushort_t*)(base + o); o += 33554432;   // act [2][32768][256]
    ushort_t* AL  = (ushort_t*)(base + o); o += 33554432;
    ushort_t* BH  = (ushort_t*)(base + o); o += 33554432;
    ushort_t* BL  = (ushort_t*)(base + o); o += 33554432;
    float* commit = (float*)(base + o);    o += 64;
    float* cb     = (float*)(base + o);    o += 8388608;    // 8 iq x 1MB
    float* cbT    = (float*)(base + o);    o += 8388608;
    float* cbn    = (float*)(base + o);    o += 32768;

    static const int DIL[4] = {3, 9, 27, 81};

    hipMemsetAsync(commit, 0, 64, stream);

    // weight prep
    wprep3_k<<<20480, 256, 0, stream>>>(erw, drw, wH3, wL3);
    wprep4_k<<<2048, 256, 0, stream>>>(edw, duw, w4H, w4L);

    // conv3 dispatch. R8 ladder (kept): d<=27 one NT notch down at 16384/8192;
    // d=81 ladder unchanged.
    auto conv3 = [&](const ushort_t* iH, const ushort_t* iL,
                     const ushort_t* wh, const ushort_t* wl, const float* bb,
                     const ushort_t* sH, const ushort_t* sL, float alpha,
                     ushort_t* oH, ushort_t* oL, int L, int d) {
        const bool db = (d <= 27);
        if (db) {
            if (L >= 32768)
                convs_k<3, 1, true, 8, 27, true><<<dim3(L / 128, 1, 2), 256, 0, stream>>>(
                    iH, iL, wh, wl, bb, sH, sL, alpha, oH, oL, L, L, d, d);
            else if (L >= 8192)
                convs_k<3, 1, true, 4, 27, true><<<dim3(L / 64, 1, 2), 256, 0, stream>>>(
                    iH, iL, wh, wl, bb, sH, sL, alpha, oH, oL, L, L, d, d);
            else if (L >= 4096)
                convs_k<3, 1, true, 2, 27, true><<<dim3(L / 32, 1, 2), 256, 0, stream>>>(
                    iH, iL, wh, wl, bb, sH, sL, alpha, oH, oL, L, L, d, d);
            else
                convs_k<3, 1, true, 1, 27, true><<<dim3(L / 16, 1, 2), 256, 0, stream>>>(
                    iH, iL, wh, wl, bb, sH, sL, alpha, oH, oL, L, L, d, d);
        } else {
            if (L >= 16384)
                convs_k<3, 1, true, 8, 81, false><<<dim3(L / 128, 1, 2), 256, 0, stream>>>(
                    iH, iL, wh, wl, bb, sH, sL, alpha, oH, oL, L, L, d, d);
            else if (L >= 8192)
                convs_k<3, 1, true, 4, 81, false><<<dim3(L / 64, 1, 2), 256, 0, stream>>>(
                    iH, iL, wh, wl, bb, sH, sL, alpha, oH, oL, L, L, d, d);
            else if (L >= 4096)
                convs_k<3, 1, true, 2, 81, false><<<dim3(L / 32, 1, 2), 256, 0, stream>>>(
                    iH, iL, wh, wl, bb, sH, sL, alpha, oH, oL, L, L, d, d);
            else
                convs_k<3, 1, true, 1, 81, false><<<dim3(L / 16, 1, 2), 256, 0, stream>>>(
                    iH, iL, wh, wl, bb, sH, sL, alpha, oH, oL, L, L, d, d);
        }
    };

    // -------------------- encoder --------------------
    down0_k2<<<dim3(32768, 2), 256, 0, stream>>>(x, ed0w, ed0b, AH, AL);
    int L = 32768;
    for (int i = 0; i < 5; ++i) {
        if (i > 0) {
            const ushort_t* wh = w4H + (size_t)(i - 1) * 262144;
            const ushort_t* wl = w4L + (size_t)(i - 1) * 262144;
            const int Lout = L / 2;
            if (Lout >= 16384)
                convs_k<4, 2, false, 8, 1, false><<<dim3(Lout / 128, 1, 2), 256, 0, stream>>>(
                    AH, AL, wh, wl, edb + (i - 1) * 256, AH, AL, 0.f, BH, BL, L, Lout, 1, 1);
            else if (Lout >= 8192)
                convs_k<4, 2, false, 4, 1, false><<<dim3(Lout / 64, 1, 2), 256, 0, stream>>>(
                    AH, AL, wh, wl, edb + (i - 1) * 256, AH, AL, 0.f, BH, BL, L, Lout, 1, 1);
            else if (Lout >= 4096)
                convs_k<4, 2, false, 2, 1, false><<<dim3(Lout / 32, 1, 2), 256, 0, stream>>>(
                    AH, AL, wh, wl, edb + (i - 1) * 256, AH, AL, 0.f, BH, BL, L, Lout, 1, 1);
            else
                convs_k<4, 2, false, 1, 1, false><<<dim3(Lout / 16, 1, 2), 256, 0, stream>>>(
                    AH, AL, wh, wl, edb + (i - 1) * 256, AH, AL, 0.f, BH, BL, L, Lout, 1, 1);
            ushort_t* t;
            t = AH; AH = BH; BH = t;
            t = AL; AL = BL; BL = t;
            L = Lout;
        }
        for (int j = 0; j < 4; ++j) {
            const int d = DIL[j];
            const size_t u = (size_t)(i * 4 + j) * 2;
            conv3(AH, AL, wH3 + (u + 0) * 196608, wL3 + (u + 0) * 196608,
                  erb + (u + 0) * 256, AH, AL, 0.f, BH, BL, L, d);
            conv3(BH, BL, wH3 + (u + 1) * 196608, wL3 + (u + 1) * 196608,
                  erb + (u + 1) * 256, AH, AL, 1.f, AH, AL, L, 1);
        }
    }

    // -------------------- RVQ (fully fused) --------------------
    rvq_cb_all_k<<<dim3(1024, 8), 256, 0, stream>>>(rsum, rusg, cb, cbT, cbn);
    rvq_all_k<<<512, 512, 0, stream>>>(AH, AL, cb, cbT, cbn, out + 131072, commit);

    // -------------------- decoder --------------------
    L = 2048;
    for (int i = 0; i < 5; ++i) {
        for (int j = 0; j < 4; ++j) {
            const int d = DIL[j];
            const size_t u = 40 + (size_t)(i * 4 + j) * 2;   // decoder slabs 40..79
            conv3(AH, AL, wH3 + (u + 0) * 196608, wL3 + (u + 0) * 196608,
                  drb + ((size_t)(i * 4 + j) * 2 + 0) * 256, AH, AL, 0.f, BH, BL, L, d);
            conv3(BH, BL, wH3 + (u + 1) * 196608, wL3 + (u + 1) * 196608,
                  drb + ((size_t)(i * 4 + j) * 2 + 1) * 256, AH, AL, 2.f, AH, AL, L, 1);
        }
        if (i < 4) {
            const ushort_t* wh = w4H + (size_t)(4 + i) * 262144;
            const ushort_t* wl = w4L + (size_t)(4 + i) * 262144;
            if (L >= 8192)
                convt_k<4><<<dim3(L / 64, 1, 2), 256, 0, stream>>>(
                    AH, AL, wh, wl, dub + i * 256, BH, BL, L);
            else if (L >= 4096)
                convt_k<2><<<dim3(L / 32, 1, 2), 256, 0, stream>>>(
                    AH, AL, wh, wl, dub + i * 256, BH, BL, L);
            else
                convt_k<1><<<dim3(L / 16, 1, 2), 256, 0, stream>>>(
                    AH, AL, wh, wl, dub + i * 256, BH, BL, L);
            ushort_t* t;
            t = AH; AH = BH; BH = t;
            t = AL; AL = BL; BL = t;
            L *= 2;
        } else {
            uplast_k2<<<dim3(L / 256, 2), 256, 0, stream>>>(AH, AL, dulw, dulb, out, L);
        }
    }

    commit_write_k<<<1, 1, 0, stream>>>(commit, out + 163840);
}